// Round 1
// baseline (215.867 us; speedup 1.0000x reference)
//
#include <hip/hip_runtime.h>
#include <math.h>

#define NRAYS 32768
#define D_DIM 16384
#define NVOX 256
#define NCH 4
#define CHUNKS 17          // 1 head chunk + 16 x-plane chunks (16 planes each)
#define RAYS_PER_BLOCK 15  // 15 * 17 = 255 threads used of 256

__device__ __forceinline__ float alpha_of(int i, float s, float sd) {
    // ((i - 0.5) - s) / sd, matching reference op order exactly (no fma)
    float p = __fsub_rn((float)i, 0.5f);
    return __fdiv_rn(__fsub_rn(p, s), sd);
}

// number of i in [0,256] with alpha(i) < t   (requires sd > 0, alpha increasing)
__device__ __forceinline__ int cnt_less(float t, float s, float sd) {
    float est = __fadd_rn(__fadd_rn(__fmul_rn(t, sd), s), 0.5f);
    int i = (int)floorf(est) - 2;
    if (i < 0) i = 0;
    if (i > 257) i = 257;
    while (i <= 256 && alpha_of(i, s, sd) < t) ++i;
    return i;
}

__global__ __launch_bounds__(256) void siddon_kernel(
    const float* __restrict__ volume,
    const float* __restrict__ src,
    const float* __restrict__ tgt,
    const float* __restrict__ maskv,
    float* __restrict__ out)
{
    __shared__ float partials[RAYS_PER_BLOCK * CHUNKS][NCH + 1]; // +1 pad vs bank conflicts

    const int tid = threadIdx.x;
    const int rl = tid / CHUNKS;          // local ray 0..14
    const int ck = tid - rl * CHUNKS;     // chunk 0..16
    const long ray = (long)blockIdx.x * RAYS_PER_BLOCK + rl;

    float acc0 = 0.f, acc1 = 0.f, acc2 = 0.f, acc3 = 0.f;

    if (tid < RAYS_PER_BLOCK * CHUNKS && ray < NRAYS) {
        const float sx = src[ray * 3 + 0];
        const float sy = src[ray * 3 + 1];
        const float sz = src[ray * 3 + 2];
        const float sdx = __fadd_rn(__fsub_rn(tgt[ray * 3 + 0], sx), 1e-8f);
        const float sdy = __fadd_rn(__fsub_rn(tgt[ray * 3 + 1], sy), 1e-8f);
        const float sdz = __fadd_rn(__fsub_rn(tgt[ray * 3 + 2], sz), 1e-8f);

        int ix, iy, iz, stopx;
        if (ck == 0) {
            ix = 0; iy = 0; iz = 0; stopx = 0;        // head: segments before x-plane 0
        } else {
            const int c = ck - 1;
            ix = 16 * c;
            const float t0 = alpha_of(ix, sx, sdx);
            iy = cnt_less(t0, sy, sdy);
            iz = cnt_less(t0, sz, sdz);
            stopx = (c == 15) ? 1000 : 16 * (c + 1);  // last chunk runs to exhaustion (tail)
        }

        const float INF = __int_as_float(0x7f800000);
        float a_prev = 0.f;
        bool first = true;

        for (int it = 0; it < 840; ++it) {
            const float ax = (ix <= NVOX) ? alpha_of(ix, sx, sdx) : INF;
            const float ay = (iy <= NVOX) ? alpha_of(iy, sy, sdy) : INF;
            const float az = (iz <= NVOX) ? alpha_of(iz, sz, sdz) : INF;

            int m; float t;
            if (ax <= ay && ax <= az) { m = 0; t = ax; }
            else if (ay <= az)        { m = 1; t = ay; }
            else                      { m = 2; t = az; }

            if (t == INF) break;                        // all exhausted (tail chunk end)
            const bool stop = (m == 0 && ix == stopx);  // about to emit next chunk's first alpha

            if (!first) {
                // segment [a_prev, t]
                const float diff = __fsub_rn(t, a_prev);
                const float mid  = __fmul_rn(0.5f, __fadd_rn(a_prev, t));
                const float px = __fadd_rn(sx, __fmul_rn(mid, sdx));
                const float py = __fadd_rn(sy, __fmul_rn(mid, sdy));
                const float pz = __fadd_rn(sz, __fmul_rn(mid, sdz));
                // g = 2*p/256 - 1 ; idx = rint((g+1)*0.5*255)  (half-to-even, like jnp.round)
                const float gx = __fsub_rn(__fdiv_rn(__fmul_rn(2.0f, px), 256.0f), 1.0f);
                const float gy = __fsub_rn(__fdiv_rn(__fmul_rn(2.0f, py), 256.0f), 1.0f);
                const float gz = __fsub_rn(__fdiv_rn(__fmul_rn(2.0f, pz), 256.0f), 1.0f);
                const float fx = rintf(__fmul_rn(__fmul_rn(__fadd_rn(gx, 1.0f), 0.5f), 255.0f));
                const float fy = rintf(__fmul_rn(__fmul_rn(__fadd_rn(gy, 1.0f), 0.5f), 255.0f));
                const float fz = rintf(__fmul_rn(__fmul_rn(__fadd_rn(gz, 1.0f), 0.5f), 255.0f));

                if (fx >= 0.f && fx <= 255.f &&
                    fy >= 0.f && fy <= 255.f &&
                    fz >= 0.f && fz <= 255.f) {
                    const int off = (((int)fx) << 16) | (((int)fy) << 8) | ((int)fz);
                    const float val = volume[off];
                    const float img = __fmul_rn(val, diff);
                    const int ch = (int)maskv[off];
                    acc0 += (ch == 0) ? img : 0.f;
                    acc1 += (ch == 1) ? img : 0.f;
                    acc2 += (ch == 2) ? img : 0.f;
                    acc3 += (ch == 3) ? img : 0.f;
                }
            }

            if (stop) break;
            a_prev = t;
            first = false;
            if (m == 0) ++ix; else if (m == 1) ++iy; else ++iz;
        }
    }

    if (tid < RAYS_PER_BLOCK * CHUNKS) {
        partials[tid][0] = acc0;
        partials[tid][1] = acc1;
        partials[tid][2] = acc2;
        partials[tid][3] = acc3;
    }
    __syncthreads();

    // deterministic per-ray reduction: 15 rays * 4 channels = 60 threads
    if (tid < RAYS_PER_BLOCK * NCH) {
        const int rl2 = tid >> 2;
        const int ch  = tid & 3;
        const long ray2 = (long)blockIdx.x * RAYS_PER_BLOCK + rl2;
        if (ray2 < NRAYS) {
            float s = 0.f;
            for (int k = 0; k < CHUNKS; ++k)
                s = __fadd_rn(s, partials[rl2 * CHUNKS + k][ch]);
            const float sx = src[ray2 * 3 + 0];
            const float sy = src[ray2 * 3 + 1];
            const float sz = src[ray2 * 3 + 2];
            const float sdx = __fadd_rn(__fsub_rn(tgt[ray2 * 3 + 0], sx), 1e-8f);
            const float sdy = __fadd_rn(__fsub_rn(tgt[ray2 * 3 + 1], sy), 1e-8f);
            const float sdz = __fadd_rn(__fsub_rn(tgt[ray2 * 3 + 2], sz), 1e-8f);
            const float rlen = sqrtf(__fadd_rn(__fadd_rn(
                __fmul_rn(sdx, sdx), __fmul_rn(sdy, sdy)), __fmul_rn(sdz, sdz)));
            const int b = (int)(ray2 >> 14);
            const int d = (int)(ray2 & (D_DIM - 1));
            out[((long)b * NCH + ch) * D_DIM + d] = __fmul_rn(s, rlen);
        }
    }
}

extern "C" void kernel_launch(void* const* d_in, const int* in_sizes, int n_in,
                              void* d_out, int out_size, void* d_ws, size_t ws_size,
                              hipStream_t stream) {
    const float* volume = (const float*)d_in[0];
    const float* src    = (const float*)d_in[1];
    const float* tgt    = (const float*)d_in[2];
    const float* maskv  = (const float*)d_in[3];
    float* out = (float*)d_out;

    const int nblocks = (NRAYS + RAYS_PER_BLOCK - 1) / RAYS_PER_BLOCK; // 2185
    siddon_kernel<<<nblocks, 256, 0, stream>>>(volume, src, tgt, maskv, out);
}

// Round 2
// 152.942 us; speedup vs baseline: 1.4114x; 1.4114x over previous
//
#include <hip/hip_runtime.h>
#include <math.h>

#define NRAYS 32768
#define D_DIM 16384
#define NVOX 256
#define NCH 4
#define CHUNKS 17          // 1 head chunk + 16 x-plane chunks (16 planes each)
#define RAYS_PER_BLOCK 15  // 15 * 17 = 255 threads used of 256

// Diagonal slab: for every in-volume sample, |y-x|<=54 and |z-x|<=54
// (|sy-sx|<=20, |sdy-sdx|<=40, alpha<=0.82 -> bound ~53; margin to 64).
#define SLAB_HALF 64
#define SLAB_W 128
#define SLAB_CELLS (256 * SLAB_W * SLAB_W)   // 4.19M cells -> 16.78 MB

__device__ __forceinline__ float alpha_of(int i, float s, float sd) {
    // ((i - 0.5) - s) / sd, matching reference op order exactly (no fma)
    float p = __fsub_rn((float)i, 0.5f);
    return __fdiv_rn(__fsub_rn(p, s), sd);
}

// number of i in [0,256] with alpha(i) < t   (requires sd > 0, alpha increasing)
__device__ __forceinline__ int cnt_less(float t, float s, float sd) {
    float est = __fadd_rn(__fadd_rn(__fmul_rn(t, sd), s), 0.5f);
    int i = (int)floorf(est) - 2;
    if (i < 0) i = 0;
    if (i > 257) i = 257;
    while (i <= 256 && alpha_of(i, s, sd) < t) ++i;
    return i;
}

// ---- prep: pack volume value (low 2 mantissa bits cleared) + mask label ----
__global__ __launch_bounds__(256) void pack_kernel(
    const float* __restrict__ vol,
    const float* __restrict__ msk,
    unsigned int* __restrict__ packed)
{
    const int idx = blockIdx.x * 256 + threadIdx.x;       // [0, SLAB_CELLS)
    const int lz = idx & (SLAB_W - 1);
    const int ly = (idx >> 7) & (SLAB_W - 1);
    const int x  = idx >> 14;
    const int y = x + ly - SLAB_HALF;
    const int z = x + lz - SLAB_HALF;
    unsigned int v = 0u;
    if ((unsigned)y < 256u && (unsigned)z < 256u) {
        const int o = (x << 16) | (y << 8) | z;
        const unsigned int u = __float_as_uint(vol[o]) & ~3u;
        v = u | ((unsigned int)msk[o] & 3u);
    }
    packed[idx] = v;
}

template<int USE_PACKED>
__global__ __launch_bounds__(256) void siddon_kernel(
    const float* __restrict__ volume,
    const float* __restrict__ src,
    const float* __restrict__ tgt,
    const float* __restrict__ maskv,
    const unsigned int* __restrict__ packed,
    float* __restrict__ out)
{
    __shared__ float partials[RAYS_PER_BLOCK * CHUNKS][NCH + 1]; // +1 pad vs bank conflicts

    const int tid = threadIdx.x;
    const int rl = tid / CHUNKS;          // local ray 0..14
    const int ck = tid - rl * CHUNKS;     // chunk 0..16
    const long ray = (long)blockIdx.x * RAYS_PER_BLOCK + rl;

    float acc0 = 0.f, acc1 = 0.f, acc2 = 0.f, acc3 = 0.f;

    if (tid < RAYS_PER_BLOCK * CHUNKS && ray < NRAYS) {
        const float sx = src[ray * 3 + 0];
        const float sy = src[ray * 3 + 1];
        const float sz = src[ray * 3 + 2];
        const float sdx = __fadd_rn(__fsub_rn(tgt[ray * 3 + 0], sx), 1e-8f);
        const float sdy = __fadd_rn(__fsub_rn(tgt[ray * 3 + 1], sy), 1e-8f);
        const float sdz = __fadd_rn(__fsub_rn(tgt[ray * 3 + 2], sz), 1e-8f);

        int ix, iy, iz, stopx;
        if (ck == 0) {
            ix = 0; iy = 0; iz = 0; stopx = 0;        // head: segments before x-plane 0
        } else {
            const int c = ck - 1;
            ix = 16 * c;
            const float t0 = alpha_of(ix, sx, sdx);
            iy = cnt_less(t0, sy, sdy);
            iz = cnt_less(t0, sz, sdz);
            stopx = (c == 15) ? 1000 : 16 * (c + 1);  // last chunk runs to exhaustion (tail)
        }

        const float INF = __int_as_float(0x7f800000);
        float a_prev = 0.f;
        bool first = true;
        const float INV256 = 0.00390625f;             // 2^-8: x*INV256 == x/256 bitwise

        for (int it = 0; it < 840; ++it) {
            const float ax = (ix <= NVOX) ? alpha_of(ix, sx, sdx) : INF;
            const float ay = (iy <= NVOX) ? alpha_of(iy, sy, sdy) : INF;
            const float az = (iz <= NVOX) ? alpha_of(iz, sz, sdz) : INF;

            int m; float t;
            if (ax <= ay && ax <= az) { m = 0; t = ax; }
            else if (ay <= az)        { m = 1; t = ay; }
            else                      { m = 2; t = az; }

            if (t == INF) break;                        // all exhausted (tail chunk end)
            const bool stop = (m == 0 && ix == stopx);  // about to emit next chunk's first alpha

            if (!first) {
                // segment [a_prev, t]
                const float diff = __fsub_rn(t, a_prev);
                const float mid  = __fmul_rn(0.5f, __fadd_rn(a_prev, t));
                const float px = __fadd_rn(sx, __fmul_rn(mid, sdx));
                const float py = __fadd_rn(sy, __fmul_rn(mid, sdy));
                const float pz = __fadd_rn(sz, __fmul_rn(mid, sdz));
                // g = 2*p/256 - 1 ; idx = rint((g+1)*0.5*255)  (half-to-even, like jnp.round)
                const float gx = __fsub_rn(__fmul_rn(__fmul_rn(2.0f, px), INV256), 1.0f);
                const float gy = __fsub_rn(__fmul_rn(__fmul_rn(2.0f, py), INV256), 1.0f);
                const float gz = __fsub_rn(__fmul_rn(__fmul_rn(2.0f, pz), INV256), 1.0f);
                const float fx = rintf(__fmul_rn(__fmul_rn(__fadd_rn(gx, 1.0f), 0.5f), 255.0f));
                const float fy = rintf(__fmul_rn(__fmul_rn(__fadd_rn(gy, 1.0f), 0.5f), 255.0f));
                const float fz = rintf(__fmul_rn(__fmul_rn(__fadd_rn(gz, 1.0f), 0.5f), 255.0f));

                if (fx >= 0.f && fx <= 255.f &&
                    fy >= 0.f && fy <= 255.f &&
                    fz >= 0.f && fz <= 255.f) {
                    const int vx = (int)fx, vy = (int)fy, vz = (int)fz;
                    float val; int ch;
                    if (USE_PACKED) {
                        const int ry = vy - vx + SLAB_HALF;
                        const int rz = vz - vx + SLAB_HALF;
                        if ((unsigned)ry < (unsigned)SLAB_W && (unsigned)rz < (unsigned)SLAB_W) {
                            const unsigned int bits = packed[(vx << 14) | (ry << 7) | rz];
                            val = __uint_as_float(bits & ~3u);
                            ch = (int)(bits & 3u);
                        } else {                       // outside slab (provably never)
                            const int off = (vx << 16) | (vy << 8) | vz;
                            val = volume[off];
                            ch = (int)maskv[off];
                        }
                    } else {
                        const int off = (vx << 16) | (vy << 8) | vz;
                        val = volume[off];
                        ch = (int)maskv[off];
                    }
                    const float img = __fmul_rn(val, diff);
                    acc0 += (ch == 0) ? img : 0.f;
                    acc1 += (ch == 1) ? img : 0.f;
                    acc2 += (ch == 2) ? img : 0.f;
                    acc3 += (ch == 3) ? img : 0.f;
                }
            }

            if (stop) break;
            a_prev = t;
            first = false;
            if (m == 0) ++ix; else if (m == 1) ++iy; else ++iz;
        }
    }

    if (tid < RAYS_PER_BLOCK * CHUNKS) {
        partials[tid][0] = acc0;
        partials[tid][1] = acc1;
        partials[tid][2] = acc2;
        partials[tid][3] = acc3;
    }
    __syncthreads();

    // deterministic per-ray reduction: 15 rays * 4 channels = 60 threads
    if (tid < RAYS_PER_BLOCK * NCH) {
        const int rl2 = tid >> 2;
        const int ch  = tid & 3;
        const long ray2 = (long)blockIdx.x * RAYS_PER_BLOCK + rl2;
        if (ray2 < NRAYS) {
            float s = 0.f;
            for (int k = 0; k < CHUNKS; ++k)
                s = __fadd_rn(s, partials[rl2 * CHUNKS + k][ch]);
            const float sx = src[ray2 * 3 + 0];
            const float sy = src[ray2 * 3 + 1];
            const float sz = src[ray2 * 3 + 2];
            const float sdx = __fadd_rn(__fsub_rn(tgt[ray2 * 3 + 0], sx), 1e-8f);
            const float sdy = __fadd_rn(__fsub_rn(tgt[ray2 * 3 + 1], sy), 1e-8f);
            const float sdz = __fadd_rn(__fsub_rn(tgt[ray2 * 3 + 2], sz), 1e-8f);
            const float rlen = sqrtf(__fadd_rn(__fadd_rn(
                __fmul_rn(sdx, sdx), __fmul_rn(sdy, sdy)), __fmul_rn(sdz, sdz)));
            const int b = (int)(ray2 >> 14);
            const int d = (int)(ray2 & (D_DIM - 1));
            out[((long)b * NCH + ch) * D_DIM + d] = __fmul_rn(s, rlen);
        }
    }
}

extern "C" void kernel_launch(void* const* d_in, const int* in_sizes, int n_in,
                              void* d_out, int out_size, void* d_ws, size_t ws_size,
                              hipStream_t stream) {
    const float* volume = (const float*)d_in[0];
    const float* src    = (const float*)d_in[1];
    const float* tgt    = (const float*)d_in[2];
    const float* maskv  = (const float*)d_in[3];
    float* out = (float*)d_out;
    unsigned int* packed = (unsigned int*)d_ws;

    const int nblocks = (NRAYS + RAYS_PER_BLOCK - 1) / RAYS_PER_BLOCK; // 2185

    if (ws_size >= (size_t)SLAB_CELLS * 4u) {
        pack_kernel<<<SLAB_CELLS / 256, 256, 0, stream>>>(volume, maskv, packed);
        siddon_kernel<1><<<nblocks, 256, 0, stream>>>(volume, src, tgt, maskv, packed, out);
    } else {
        siddon_kernel<0><<<nblocks, 256, 0, stream>>>(volume, src, tgt, maskv, packed, out);
    }
}

// Round 4
// 149.663 us; speedup vs baseline: 1.4424x; 1.0219x over previous
//
#include <hip/hip_runtime.h>
#include <math.h>

#define NRAYS 32768
#define D_DIM 16384
#define NVOX 256
#define NCH 4
#define CHUNKS 17          // 1 head chunk + 16 x-plane chunks (16 planes each)
#define RAYS_PER_BLOCK 15  // 15 * 17 = 255 threads used of 256

// Diagonal slab: for every in-volume sample, |y-x|<=54 and |z-x|<=54
// (|sy-sx|<=20, |sdy-sdx|<=40, alpha<=0.82 -> bound ~53; margin to 64).
#define SLAB_HALF 64
#define SLAB_W 128
#define SLAB_CELLS (256 * SLAB_W * SLAB_W)   // 4.19M cells -> 16.78 MB

__device__ __forceinline__ float alpha_of(int i, float s, float sd) {
    // ((i - 0.5) - s) / sd, matching reference op order exactly (no fma)
    float p = __fsub_rn((float)i, 0.5f);
    return __fdiv_rn(__fsub_rn(p, s), sd);
}

__device__ __forceinline__ float alpha_of_f(float fi, float s, float sd) {
    // fi == (float)i exactly; same bitwise result as alpha_of
    float p = __fsub_rn(fi, 0.5f);
    return __fdiv_rn(__fsub_rn(p, s), sd);
}

// number of i in [0,256] with alpha(i) < t   (requires sd > 0, alpha increasing)
__device__ __forceinline__ int cnt_less(float t, float s, float sd) {
    float est = __fadd_rn(__fadd_rn(__fmul_rn(t, sd), s), 0.5f);
    int i = (int)floorf(est) - 2;
    if (i < 0) i = 0;
    if (i > 257) i = 257;
    while (i <= 256 && alpha_of(i, s, sd) < t) ++i;
    return i;
}

// ---- prep: pack volume value (low 2 mantissa bits cleared) + mask label ----
__global__ __launch_bounds__(256) void pack_kernel(
    const float* __restrict__ vol,
    const float* __restrict__ msk,
    unsigned int* __restrict__ packed)
{
    const int idx = blockIdx.x * 256 + threadIdx.x;       // [0, SLAB_CELLS)
    const int lz = idx & (SLAB_W - 1);
    const int ly = (idx >> 7) & (SLAB_W - 1);
    const int x  = idx >> 14;
    const int y = x + ly - SLAB_HALF;
    const int z = x + lz - SLAB_HALF;
    unsigned int v = 0u;
    if ((unsigned)y < 256u && (unsigned)z < 256u) {
        const int o = (x << 16) | (y << 8) | z;
        const unsigned int u = __float_as_uint(vol[o]) & ~3u;
        v = u | ((unsigned int)msk[o] & 3u);
    }
    packed[idx] = v;
}

template<int USE_PACKED>
__global__ __launch_bounds__(256) void siddon_kernel(
    const float* __restrict__ volume,
    const float* __restrict__ src,
    const float* __restrict__ tgt,
    const float* __restrict__ maskv,
    const unsigned int* __restrict__ packed,
    float* __restrict__ out)
{
    __shared__ float partials[RAYS_PER_BLOCK * CHUNKS][NCH + 1]; // +1 pad vs bank conflicts

    const int tid = threadIdx.x;
    const int rl = tid / CHUNKS;          // local ray 0..14
    const int ck = tid - rl * CHUNKS;     // chunk 0..16
    const long ray = (long)blockIdx.x * RAYS_PER_BLOCK + rl;

    float acc0 = 0.f, acc1 = 0.f, acc2 = 0.f, acc3 = 0.f;

    if (tid < RAYS_PER_BLOCK * CHUNKS && ray < NRAYS) {
        const float sx = src[ray * 3 + 0];
        const float sy = src[ray * 3 + 1];
        const float sz = src[ray * 3 + 2];
        const float sdx = __fadd_rn(__fsub_rn(tgt[ray * 3 + 0], sx), 1e-8f);
        const float sdy = __fadd_rn(__fsub_rn(tgt[ray * 3 + 1], sy), 1e-8f);
        const float sdz = __fadd_rn(__fsub_rn(tgt[ray * 3 + 2], sz), 1e-8f);

        int ix, iy, iz, stopx;
        if (ck == 0) {
            ix = 0; iy = 0; iz = 0; stopx = 0;        // head: segments before x-plane 0
        } else {
            const int c = ck - 1;
            ix = 16 * c;
            const float t0 = alpha_of(ix, sx, sdx);
            iy = cnt_less(t0, sy, sdy);
            iz = cnt_less(t0, sz, sdz);
            stopx = (c == 15) ? 1000 : 16 * (c + 1);  // last chunk runs to exhaustion (tail)
        }

        const float INF = __int_as_float(0x7f800000);
        const float INV256 = 0.00390625f;             // 2^-8: x*INV256 == x/256 bitwise

        // cached frontier alphas (recomputed only on advance) + exact float indices
        float fx_i = (float)ix, fy_i = (float)iy, fz_i = (float)iz;
        float ax = (ix <= NVOX) ? alpha_of_f(fx_i, sx, sdx) : INF;
        float ay = (iy <= NVOX) ? alpha_of_f(fy_i, sy, sdy) : INF;
        float az = (iz <= NVOX) ? alpha_of_f(fz_i, sz, sdz) : INF;

        float a_prev = 0.f;
        bool first = true;

        for (int it = 0; it < 840; ++it) {
            int m; float t;
            if (ax <= ay && ax <= az) { m = 0; t = ax; }
            else if (ay <= az)        { m = 1; t = ay; }
            else                      { m = 2; t = az; }

            if (t == INF) break;                        // all exhausted (tail chunk end)
            const bool stop = (m == 0 && ix == stopx);  // this alpha is the next chunk's first

            // advance the winning axis first: the division overlaps the body below.
            // (Harmless when stop: we break after the emit regardless.)
            if (m == 0) {
                ++ix; fx_i = __fadd_rn(fx_i, 1.0f);
                ax = (ix <= NVOX) ? alpha_of_f(fx_i, sx, sdx) : INF;
            } else if (m == 1) {
                ++iy; fy_i = __fadd_rn(fy_i, 1.0f);
                ay = (iy <= NVOX) ? alpha_of_f(fy_i, sy, sdy) : INF;
            } else {
                ++iz; fz_i = __fadd_rn(fz_i, 1.0f);
                az = (iz <= NVOX) ? alpha_of_f(fz_i, sz, sdz) : INF;
            }

            if (!first) {
                // segment [a_prev, t] — emitted even on the stop iteration (chunk's last)
                const float diff = __fsub_rn(t, a_prev);
                const float mid  = __fmul_rn(0.5f, __fadd_rn(a_prev, t));
                const float px = __fadd_rn(sx, __fmul_rn(mid, sdx));
                const float py = __fadd_rn(sy, __fmul_rn(mid, sdy));
                const float pz = __fadd_rn(sz, __fmul_rn(mid, sdz));
                // g = 2*p/256 - 1 ; idx = rint((g+1)*0.5*255)  (half-to-even, like jnp.round)
                const float gx = __fsub_rn(__fmul_rn(__fmul_rn(2.0f, px), INV256), 1.0f);
                const float gy = __fsub_rn(__fmul_rn(__fmul_rn(2.0f, py), INV256), 1.0f);
                const float gz = __fsub_rn(__fmul_rn(__fmul_rn(2.0f, pz), INV256), 1.0f);
                const float fx = rintf(__fmul_rn(__fmul_rn(__fadd_rn(gx, 1.0f), 0.5f), 255.0f));
                const float fy = rintf(__fmul_rn(__fmul_rn(__fadd_rn(gy, 1.0f), 0.5f), 255.0f));
                const float fz = rintf(__fmul_rn(__fmul_rn(__fadd_rn(gz, 1.0f), 0.5f), 255.0f));

                if (fx >= 0.f && fx <= 255.f &&
                    fy >= 0.f && fy <= 255.f &&
                    fz >= 0.f && fz <= 255.f) {
                    const int vx = (int)fx, vy = (int)fy, vz = (int)fz;
                    float val; int ch;
                    if (USE_PACKED) {
                        const int ry = vy - vx + SLAB_HALF;
                        const int rz = vz - vx + SLAB_HALF;
                        if ((unsigned)ry < (unsigned)SLAB_W && (unsigned)rz < (unsigned)SLAB_W) {
                            const unsigned int bits = packed[(vx << 14) | (ry << 7) | rz];
                            val = __uint_as_float(bits & ~3u);
                            ch = (int)(bits & 3u);
                        } else {                       // outside slab (provably never)
                            const int off = (vx << 16) | (vy << 8) | vz;
                            val = volume[off];
                            ch = (int)maskv[off];
                        }
                    } else {
                        const int off = (vx << 16) | (vy << 8) | vz;
                        val = volume[off];
                        ch = (int)maskv[off];
                    }
                    const float img = __fmul_rn(val, diff);
                    acc0 += (ch == 0) ? img : 0.f;
                    acc1 += (ch == 1) ? img : 0.f;
                    acc2 += (ch == 2) ? img : 0.f;
                    acc3 += (ch == 3) ? img : 0.f;
                }
            }

            if (stop) break;
            a_prev = t;
            first = false;
        }
    }

    if (tid < RAYS_PER_BLOCK * CHUNKS) {
        partials[tid][0] = acc0;
        partials[tid][1] = acc1;
        partials[tid][2] = acc2;
        partials[tid][3] = acc3;
    }
    __syncthreads();

    // deterministic per-ray reduction: 15 rays * 4 channels = 60 threads
    if (tid < RAYS_PER_BLOCK * NCH) {
        const int rl2 = tid >> 2;
        const int ch  = tid & 3;
        const long ray2 = (long)blockIdx.x * RAYS_PER_BLOCK + rl2;
        if (ray2 < NRAYS) {
            float s = 0.f;
            for (int k = 0; k < CHUNKS; ++k)
                s = __fadd_rn(s, partials[rl2 * CHUNKS + k][ch]);
            const float sx = src[ray2 * 3 + 0];
            const float sy = src[ray2 * 3 + 1];
            const float sz = src[ray2 * 3 + 2];
            const float sdx = __fadd_rn(__fsub_rn(tgt[ray2 * 3 + 0], sx), 1e-8f);
            const float sdy = __fadd_rn(__fsub_rn(tgt[ray2 * 3 + 1], sy), 1e-8f);
            const float sdz = __fadd_rn(__fsub_rn(tgt[ray2 * 3 + 2], sz), 1e-8f);
            const float rlen = sqrtf(__fadd_rn(__fadd_rn(
                __fmul_rn(sdx, sdx), __fmul_rn(sdy, sdy)), __fmul_rn(sdz, sdz)));
            const int b = (int)(ray2 >> 14);
            const int d = (int)(ray2 & (D_DIM - 1));
            out[((long)b * NCH + ch) * D_DIM + d] = __fmul_rn(s, rlen);
        }
    }
}

extern "C" void kernel_launch(void* const* d_in, const int* in_sizes, int n_in,
                              void* d_out, int out_size, void* d_ws, size_t ws_size,
                              hipStream_t stream) {
    const float* volume = (const float*)d_in[0];
    const float* src    = (const float*)d_in[1];
    const float* tgt    = (const float*)d_in[2];
    const float* maskv  = (const float*)d_in[3];
    float* out = (float*)d_out;
    unsigned int* packed = (unsigned int*)d_ws;

    const int nblocks = (NRAYS + RAYS_PER_BLOCK - 1) / RAYS_PER_BLOCK; // 2185

    if (ws_size >= (size_t)SLAB_CELLS * 4u) {
        pack_kernel<<<SLAB_CELLS / 256, 256, 0, stream>>>(volume, maskv, packed);
        siddon_kernel<1><<<nblocks, 256, 0, stream>>>(volume, src, tgt, maskv, packed, out);
    } else {
        siddon_kernel<0><<<nblocks, 256, 0, stream>>>(volume, src, tgt, maskv, packed, out);
    }
}